// Round 3
// baseline (8852.714 us; speedup 1.0000x reference)
//
#include <hip/hip_runtime.h>
#include <hip/hip_bf16.h>

#define TT  512
#define BB  64
#define NII 1024
#define NHH 1024
#define NBLK 256

typedef __attribute__((ext_vector_type(8))) short bf16x8;
typedef __attribute__((ext_vector_type(4))) float f32x4;

#define WPK_BYTES (256ull * 64 * 64 * 8 * 2)          // 16 MiB packed weights
#define HPK_BYTES (4ull * 32 * 64 * 8 * 2)            // 128 KiB packed H frags
#define XPK_BYTES (512ull * 4 * 32 * 64 * 8 * 2)      // 64 MiB packed x frags

__device__ __forceinline__ float sigmoidf_(float x) { return 1.0f / (1.0f + __expf(-x)); }

__device__ __forceinline__ short f2bf(float f) {
    union { __hip_bfloat16 b; short s; } u; u.b = __float2bfloat16(f); return u.s;
}

// device-coherent (bypass L1/L2) 16B load as two volatile u64 loads
__device__ __forceinline__ bf16x8 ldcg(const short* p) {
    const volatile unsigned long long* q = (const volatile unsigned long long*)p;
    unsigned long long a = q[0];
    unsigned long long b = q[1];
    union { unsigned long long u[2]; bf16x8 v; } u;
    u.u[0] = a; u.u[1] = b; return u.v;
}

// ---------------------------------------------------------------------------
// Pack 8 weight matrices into MFMA-B-fragment-major bf16 (verified round 2).
// wpk[((b*64 + kk)*64 + l)*8 + e] = Wfused[kk*32 + (l>>4)*8 + e][col = b*4 + ((l&15)&3), gate = (l&15)>>2]
// ---------------------------------------------------------------------------
__global__ __launch_bounds__(256)
void pack_weights_kernel(const float* __restrict__ Wxf, const float* __restrict__ Whf,
                         const float* __restrict__ Wxi, const float* __restrict__ Whi,
                         const float* __restrict__ Wxc, const float* __restrict__ Whc,
                         const float* __restrict__ Wxo, const float* __restrict__ Who,
                         short* __restrict__ wpk)
{
    const int b = blockIdx.x;
    const int t = threadIdx.x;
    const float* Wx[4] = { Wxf, Wxi, Wxc, Wxo };
    const float* Wh[4] = { Whf, Whi, Whc, Who };

    for (int i = 0; i < 16; ++i) {
        const int pair = t + i * 256;
        const int kk = pair >> 6;
        const int l  = pair & 63;
        const int n  = l & 15;
        const int g  = n >> 2;
        const int col = b * 4 + (n & 3);
        const int kf0 = kk * 32 + (l >> 4) * 8;
        const float* src = (kf0 < 1024) ? (Wx[g] + (size_t)kf0 * NHH + col)
                                        : (Wh[g] + (size_t)(kf0 - 1024) * NHH + col);
        short v[8];
        #pragma unroll
        for (int e = 0; e < 8; ++e) v[e] = f2bf(src[(size_t)e * NHH]);
        short* dst = wpk + ((size_t)(b * 64 + kk) * 64 + l) * 8;
        *reinterpret_cast<bf16x8*>(dst) = *reinterpret_cast<bf16x8*>(v);
    }
}

// ---------------------------------------------------------------------------
// Pack x (fp32 [T][64][1024]) into bf16 A-fragments: xpk[t][mi][kk][l][8]
// element = x[t][mi*16 + (l&15)][kk*32 + (l>>4)*8 + e]
// ---------------------------------------------------------------------------
__global__ __launch_bounds__(256)
void pack_x_kernel(const float* __restrict__ x, short* __restrict__ xpk)
{
    const int t = blockIdx.x;
    const float* xt = x + (size_t)t * BB * NII;
    short* dst = xpk + (size_t)t * 65536;

    for (int i = 0; i < 32; ++i) {
        const int d  = threadIdx.x + i * 256;     // 0..8191 fragment-chunks
        const int mi = d >> 11;
        const int kk = (d >> 6) & 31;
        const int l  = d & 63;
        const int m  = mi * 16 + (l & 15);
        const int k0 = kk * 32 + ((l >> 4) << 3);
        const float* s = xt + (size_t)m * NII + k0;
        f32x4 a0 = *reinterpret_cast<const f32x4*>(s);
        f32x4 a1 = *reinterpret_cast<const f32x4*>(s + 4);
        short v[8];
        #pragma unroll
        for (int e = 0; e < 4; ++e) { v[e] = f2bf(a0[e]); v[4 + e] = f2bf(a1[e]); }
        *reinterpret_cast<bf16x8*>(dst + (size_t)d * 8) = *reinterpret_cast<bf16x8*>(v);
    }
}

// ---------------------------------------------------------------------------
// Persistent LSTM: all 512 timesteps in one kernel, grid barrier per step.
// 256 blocks x 512 threads; block b owns hidden cols b*4..b*4+3 (x4 gates).
// Wave w: mi = w&3 (16-batch tile), kh = w>>2 (K half). Weights in LDS.
// ---------------------------------------------------------------------------
__global__ __launch_bounds__(512, 1)
void lstm_persistent(const float* __restrict__ x,       // fallback fp32 path
                     const short* __restrict__ xpk,     // packed x (optional)
                     const short* __restrict__ wpk,
                     const float* __restrict__ bfv, const float* __restrict__ biv,
                     const float* __restrict__ bcv, const float* __restrict__ bov,
                     float* __restrict__ out,
                     short* __restrict__ hpk0, short* __restrict__ hpk1,
                     unsigned* __restrict__ bar,
                     int use_xpk)
{
    __shared__ short lds_w[64 * 64 * 8];   // 64 KiB: this block's weights, frag-major
    __shared__ float red[4][64][4];        // kh=1 partials
    __shared__ float gates[4][16][16];     // pre-activation gates
    __shared__ float Cst[256];             // C state: [m*4 + jl]
    __shared__ short hstage[256];          // bf16 H staging for packed write
    extern __shared__ char dynpad[];       // launch passes extra LDS -> 1 block/CU

    const int tid = threadIdx.x;
    const int w   = tid >> 6;
    const int l   = tid & 63;
    const int mi  = w & 3;
    const int kh  = w >> 2;
    const int b   = blockIdx.x;
    (void)dynpad;

    // stage this block's 64 KiB weight chunk into LDS
    {
        const short* wsrc = wpk + (size_t)b * 32768;
        #pragma unroll
        for (int i = 0; i < 8; ++i) {
            const int c = tid + i * 512;
            *reinterpret_cast<bf16x8*>(&lds_w[c * 8]) =
                *reinterpret_cast<const bf16x8*>(&wsrc[(size_t)c * 8]);
        }
    }
    if (tid < 256) Cst[tid] = 0.0f;

    float B4[4] = {0.f, 0.f, 0.f, 0.f};
    if (tid < 256) {
        const int j = b * 4 + (tid & 3);
        B4[0] = bfv[j]; B4[1] = biv[j]; B4[2] = bcv[j]; B4[3] = bov[j];
    }
    __syncthreads();

    // packed-H write coords for wave 0 (j-range b*4..b*4+3 is within one octet)
    const int kk2 = b >> 3;
    const int lg  = (b >> 1) & 3;
    const int e0  = (b & 1) * 4;

    #pragma unroll 1
    for (int t = 0; t < TT; ++t) {
        const short* hpk_cur = (t & 1) ? hpk1 : hpk0;
        short*       hpk_nxt = (t & 1) ? hpk0 : hpk1;

        f32x4 acc0 = {0.f, 0.f, 0.f, 0.f};
        f32x4 acc1 = {0.f, 0.f, 0.f, 0.f};
        const short* wl = &lds_w[((kh * 32) * 64 + l) * 8];

        if (kh == 0) {
            if (use_xpk) {
                const short* ap = xpk + (size_t)t * 65536 + ((size_t)(mi * 32) * 64 + l) * 8;
                #pragma unroll 4
                for (int kk = 0; kk < 32; kk += 2) {
                    bf16x8 a0 = *reinterpret_cast<const bf16x8*>(ap);
                    bf16x8 b0 = *reinterpret_cast<const bf16x8*>(wl);
                    bf16x8 a1 = *reinterpret_cast<const bf16x8*>(ap + 512);
                    bf16x8 b1 = *reinterpret_cast<const bf16x8*>(wl + 512);
                    acc0 = __builtin_amdgcn_mfma_f32_16x16x32_bf16(a0, b0, acc0, 0, 0, 0);
                    acc1 = __builtin_amdgcn_mfma_f32_16x16x32_bf16(a1, b1, acc1, 0, 0, 0);
                    ap += 1024; wl += 1024;
                }
            } else {
                const float* apf = x + (size_t)t * BB * NII + (size_t)(mi * 16 + (l & 15)) * NII + (l >> 4) * 8;
                #pragma unroll 4
                for (int kk = 0; kk < 32; kk += 2) {
                    f32x4 a0 = *reinterpret_cast<const f32x4*>(apf);
                    f32x4 a1 = *reinterpret_cast<const f32x4*>(apf + 4);
                    bf16x8 b0 = *reinterpret_cast<const bf16x8*>(wl);
                    f32x4 a2 = *reinterpret_cast<const f32x4*>(apf + 32);
                    f32x4 a3 = *reinterpret_cast<const f32x4*>(apf + 36);
                    bf16x8 b1 = *reinterpret_cast<const bf16x8*>(wl + 512);
                    bf16x8 f0, f1;
                    f0[0]=f2bf(a0[0]); f0[1]=f2bf(a0[1]); f0[2]=f2bf(a0[2]); f0[3]=f2bf(a0[3]);
                    f0[4]=f2bf(a1[0]); f0[5]=f2bf(a1[1]); f0[6]=f2bf(a1[2]); f0[7]=f2bf(a1[3]);
                    f1[0]=f2bf(a2[0]); f1[1]=f2bf(a2[1]); f1[2]=f2bf(a2[2]); f1[3]=f2bf(a2[3]);
                    f1[4]=f2bf(a3[0]); f1[5]=f2bf(a3[1]); f1[6]=f2bf(a3[2]); f1[7]=f2bf(a3[3]);
                    acc0 = __builtin_amdgcn_mfma_f32_16x16x32_bf16(f0, b0, acc0, 0, 0, 0);
                    acc1 = __builtin_amdgcn_mfma_f32_16x16x32_bf16(f1, b1, acc1, 0, 0, 0);
                    apf += 64; wl += 1024;
                }
            }
        } else {
            // H half: device-coherent fragment loads (bypass stale L2)
            const short* ap = hpk_cur + ((size_t)(mi * 32) * 64 + l) * 8;
            #pragma unroll 4
            for (int kk = 0; kk < 32; kk += 2) {
                bf16x8 a0 = ldcg(ap);
                bf16x8 b0 = *reinterpret_cast<const bf16x8*>(wl);
                bf16x8 a1 = ldcg(ap + 512);
                bf16x8 b1 = *reinterpret_cast<const bf16x8*>(wl + 512);
                acc0 = __builtin_amdgcn_mfma_f32_16x16x32_bf16(a0, b0, acc0, 0, 0, 0);
                acc1 = __builtin_amdgcn_mfma_f32_16x16x32_bf16(a1, b1, acc1, 0, 0, 0);
                ap += 1024; wl += 1024;
            }
        }
        acc0[0] += acc1[0]; acc0[1] += acc1[1]; acc0[2] += acc1[2]; acc0[3] += acc1[3];

        if (kh == 1) {
            red[mi][l][0] = acc0[0]; red[mi][l][1] = acc0[1];
            red[mi][l][2] = acc0[2]; red[mi][l][3] = acc0[3];
        }
        __syncthreads();

        if (kh == 0) {
            #pragma unroll
            for (int r = 0; r < 4; ++r)
                gates[mi][(l >> 4) * 4 + r][l & 15] = acc0[r] + red[mi][l][r];
        }
        __syncthreads();

        if (tid < 256) {
            const int m   = tid >> 2;
            const int jl  = tid & 3;
            const int mi2 = m >> 4, ml = m & 15;
            const int j   = b * 4 + jl;

            const float F  = sigmoidf_(gates[mi2][ml][jl]      + B4[0]);
            const float I  = sigmoidf_(gates[mi2][ml][4 + jl]  + B4[1]);
            const float Ct = tanhf   (gates[mi2][ml][8 + jl]   + B4[2]);
            const float O  = sigmoidf_(gates[mi2][ml][12 + jl] + B4[3]);

            const float c  = Cst[tid];
            const float cn = F * c + I * Ct;
            const float hn = O * tanhf(cn);
            Cst[tid]    = cn;
            hstage[tid] = f2bf(hn);

            __builtin_nontemporal_store(hn, &out[(size_t)t * BB * NHH + (size_t)m * NHH + j]);
            if (t == TT - 1) {
                float* tail = out + (size_t)TT * BB * NHH;
                tail[(size_t)m * NHH + j]            = hn;
                tail[(size_t)BB * NHH + (size_t)m * NHH + j] = cn;
            }
        }
        __syncthreads();

        // wave 0: publish packed H (device-coherent 8B stores), then release
        if (w == 0) {
            const int mi2 = l >> 4, ml = l & 15;
            const unsigned long long hv =
                *reinterpret_cast<const unsigned long long*>(&hstage[l * 4]);
            const size_t off = ((size_t)(mi2 * 32 + kk2) * 64 + lg * 16 + ml) * 8 + e0;
            *(volatile unsigned long long*)(hpk_nxt + off) = hv;
            asm volatile("s_waitcnt vmcnt(0)" ::: "memory");
        }
        __syncthreads();

        if (tid == 0) {
            unsigned old = __hip_atomic_fetch_add(&bar[0], 1u, __ATOMIC_RELAXED, __HIP_MEMORY_SCOPE_AGENT);
            if (old == (unsigned)(t + 1) * NBLK - 1u)
                __hip_atomic_store(&bar[1], (unsigned)(t + 1), __ATOMIC_RELAXED, __HIP_MEMORY_SCOPE_AGENT);
            while (__hip_atomic_load(&bar[1], __ATOMIC_RELAXED, __HIP_MEMORY_SCOPE_AGENT) < (unsigned)(t + 1))
                __builtin_amdgcn_s_sleep(2);
        }
        __syncthreads();
    }
}

extern "C" void kernel_launch(void* const* d_in, const int* in_sizes, int n_in,
                              void* d_out, int out_size, void* d_ws, size_t ws_size,
                              hipStream_t stream) {
    const float* inputs = (const float*)d_in[0];
    const float* Wxf = (const float*)d_in[1],  *Whf = (const float*)d_in[2],  *bf = (const float*)d_in[3];
    const float* Wxi = (const float*)d_in[4],  *Whi = (const float*)d_in[5],  *bi = (const float*)d_in[6];
    const float* Wxc = (const float*)d_in[7],  *Whc = (const float*)d_in[8],  *bc = (const float*)d_in[9];
    const float* Wxo = (const float*)d_in[10], *Who = (const float*)d_in[11], *bo = (const float*)d_in[12];

    float* out = (float*)d_out;
    char*  wsb = (char*)d_ws;

    short*    wpk  = (short*)wsb;
    short*    hpk0 = (short*)(wsb + WPK_BYTES);
    short*    hpk1 = (short*)(wsb + WPK_BYTES + HPK_BYTES);
    unsigned* bar  = (unsigned*)(wsb + WPK_BYTES + 2 * HPK_BYTES);
    short*    xpk  = (short*)(wsb + WPK_BYTES + 2 * HPK_BYTES + 4096);

    const size_t need = WPK_BYTES + 2 * HPK_BYTES + 4096 + XPK_BYTES;
    const int use_xpk = (ws_size >= need) ? 1 : 0;

    // zero H0 ping-pong buffers + barrier (every launch: graph replays include it)
    hipMemsetAsync(hpk0, 0, 2 * HPK_BYTES + 4096, stream);

    pack_weights_kernel<<<dim3(256), dim3(256), 0, stream>>>(
        Wxf, Whf, Wxi, Whi, Wxc, Whc, Wxo, Who, wpk);

    if (use_xpk)
        pack_x_kernel<<<dim3(TT), dim3(256), 0, stream>>>(inputs, xpk);

    // 12 KiB dynamic LDS pad -> static 73.5 KiB + pad > 80 KiB => 1 block/CU,
    // so 256 blocks are guaranteed co-resident on 256 CUs (grid barrier safe).
    lstm_persistent<<<dim3(NBLK), dim3(512), 12288, stream>>>(
        inputs, xpk, wpk, bf, bi, bc, bo, out, hpk0, hpk1, bar, use_xpk);
}